// Round 1
// baseline (227.298 us; speedup 1.0000x reference)
//
#include <hip/hip_runtime.h>
#include <hip/hip_bf16.h>
#include <hip/hip_fp16.h>

// CRF NLL, B=256, T=1024, L=64.
// Hybrid decomposition: per batch, fwd vector chain covers emissions [0,128),
// nm=(sl-128)>>7 MFMA "matrix" segments cover [128, 128*(1+nm)) as 64x64
// linear-domain products M_s = prod(diag(E_t) V^T), bwd vector chain covers the
// <=127-step tail. combine_kernel folds v <- M_s v and reduces.
// Matrix segments: f16 MFMA 32x32x16, fp32 accum, per-step exact pow-2 renorm
// (ref = sum of 16 C-entries, folded into next step's diag(E) scalars).
// C->B repack is lane-local + v_permlane32_swap_b32 half exchanges.

typedef _Float16 h2 __attribute__((ext_vector_type(2)));
typedef _Float16 half8 __attribute__((ext_vector_type(8)));
typedef float f32x16 __attribute__((ext_vector_type(16)));
typedef unsigned u32x2 __attribute__((ext_vector_type(2)));
typedef unsigned u32x4 __attribute__((ext_vector_type(4)));

#define B2U(x) __builtin_bit_cast(unsigned, x)
#define U2H(x) __builtin_bit_cast(h2, x)
#define L2E 1.44269504088896340736f
#define LN2 0.69314718055994530942f
#define EXPE(p) __builtin_amdgcn_exp2f((p) * L2E)
#define SBAR __builtin_amdgcn_sched_barrier(0)

// ---------------- vector-chain machinery (unchanged, verified) ----------------

#define W_ALL(M) M(0) M(1) M(2) M(3) M(4) M(5) M(6) M(7) M(8) M(9) M(10) M(11) \
 M(12) M(13) M(14) M(15) M(16) M(17) M(18) M(19) M(20) M(21) M(22) M(23) M(24) \
 M(25) M(26) M(27) M(28) M(29) M(30) M(31)

#define DECLW(q) unsigned W##q;
#define LOADF(q) W##q = B2U(__builtin_amdgcn_cvt_pkrtz(EXPE(tcol[(2*(q))*66]), EXPE(tcol[(2*(q)+1)*66])));
#define LOADB(q) W##q = B2U(__builtin_amdgcn_cvt_pkrtz(EXPE(trow[2*(q)]), EXPE(trow[2*(q)+1])));
#define PINW(q)  asm volatile("" : "+v"(W##q));

#define RLD(q) int u##q = __builtin_amdgcn_readlane((int)P, 2*(q));
#define RL16A RLD(0) RLD(1) RLD(2) RLD(3) RLD(4) RLD(5) RLD(6) RLD(7) \
              RLD(8) RLD(9) RLD(10) RLD(11) RLD(12) RLD(13) RLD(14) RLD(15)
#define RL16B RLD(16) RLD(17) RLD(18) RLD(19) RLD(20) RLD(21) RLD(22) RLD(23) \
              RLD(24) RLD(25) RLD(26) RLD(27) RLD(28) RLD(29) RLD(30) RLD(31)

#if __has_builtin(__builtin_amdgcn_fdot2)
#define DOTQ(q, acc) acc = __builtin_amdgcn_fdot2(U2H((unsigned)u##q), U2H(W##q), acc, false);
#else
#define DOTQ(q, acc) { h2 _u = U2H((unsigned)u##q), _w = U2H(W##q); \
    acc = fmaf((float)_u[0], (float)_w[0], fmaf((float)_u[1], (float)_w[1], acc)); }
#endif
#define DOT16A \
    DOTQ(0,s0)  DOTQ(1,s1)  DOTQ(2,s2)  DOTQ(3,s3)  DOTQ(4,s0)  DOTQ(5,s1) \
    DOTQ(6,s2)  DOTQ(7,s3)  DOTQ(8,s0)  DOTQ(9,s1)  DOTQ(10,s2) DOTQ(11,s3) \
    DOTQ(12,s0) DOTQ(13,s1) DOTQ(14,s2) DOTQ(15,s3)
#define DOT16B \
    DOTQ(16,s0) DOTQ(17,s1) DOTQ(18,s2) DOTQ(19,s3) DOTQ(20,s0) DOTQ(21,s1) \
    DOTQ(22,s2) DOTQ(23,s3) DOTQ(24,s0) DOTQ(25,s1) DOTQ(26,s2) DOTQ(27,s3) \
    DOTQ(28,s0) DOTQ(29,s1) DOTQ(30,s2) DOTQ(31,s3)

#define ROWF(i) pb[(((i) < 0) ? 0 : (((i) > 1023) ? 1023 : (i))) * 64]

#define DPPSWAP(x) __uint_as_float((unsigned)__builtin_amdgcn_mov_dpp( \
    (int)__float_as_uint(x), 0xB1, 0xF, 0xF, true))

#define STEPX(E) { \
    unsigned abits = (unsigned)__builtin_amdgcn_readfirstlane((int)__float_as_uint(a)); \
    int k = (int)((abits >> 23) & 255u) - 122; \
    K += k; \
    float sc = __uint_as_float((unsigned)(127 - k) << 23); \
    float x = FWD ? a * sc : (a * sc) * (E); \
    float xo = DPPSWAP(x); \
    unsigned P = B2U(__builtin_amdgcn_cvt_pkrtz(x, xo)); \
    float s0 = 0.f, s1 = 0.f, s2 = 0.f, s3 = 0.f; \
    RL16A \
    SBAR; \
    DOT16A \
    RL16B \
    SBAR; \
    DOT16B \
    float s = (s0 + s1) + (s2 + s3); \
    a = FWD ? s * (E) : s; }

template<bool FWD>
__device__ __forceinline__ void chain(const float* __restrict__ pred,
                                      const float* __restrict__ trans,
                                      int b, int lane, int sl, int h,
                                      float* __restrict__ wsV,
                                      int* __restrict__ wsK)
{
    const float* pb   = pred + (size_t)b * 65536 + lane;
    const float* tcol = trans + lane;        // fwd: V[i][lane]
    const float* trow = trans + lane * 66;   // bwd: V[lane][i]
    (void)tcol; (void)trow;

    W_ALL(DECLW)
    if (FWD) { W_ALL(LOADF) } else { W_ALL(LOADB) }
    W_ALL(PINW)

    float a;
    int   K = 0;
    if (FWD) a = __builtin_amdgcn_exp2f((pb[0] + trans[64 * 66 + lane]) * L2E);
    else     a = __builtin_amdgcn_exp2f(trow[65] * L2E);

    const int dir = FWD ? 1 : -1;
    int n = FWD ? h - 1 : sl - h;
    int r = FWD ? 1 : sl - 1;

    float E0 = EXPE(ROWF(r)), E1 = EXPE(ROWF(r + dir)),
          E2 = EXPE(ROWF(r + 2 * dir)), E3 = EXPE(ROWF(r + 3 * dir));
    while (n >= 4) {
        float F0 = ROWF(r + 4 * dir), F1 = ROWF(r + 5 * dir),
              F2 = ROWF(r + 6 * dir), F3 = ROWF(r + 7 * dir);
        STEPX(E0) STEPX(E1) STEPX(E2) STEPX(E3)
        E0 = EXPE(F0); E1 = EXPE(F1); E2 = EXPE(F2); E3 = EXPE(F3);
        r += 4 * dir; n -= 4;
    }
    if (n > 0) { STEPX(E0) --n; }
    if (n > 0) { STEPX(E1) --n; }
    if (n > 0) { STEPX(E2) }

    wsV[b * 64 + lane] = a;
    if (lane == 0) wsK[b] = K;
}

// ---------------- matrix-segment machinery ----------------

#define MFMA16(a, b, c) __builtin_amdgcn_mfma_f32_32x32x16_f16(a, b, c, 0, 0, 0)

// Repack one 8-reg group of a C tile (f32, measured layout: col=lane&31,
// row=(reg&3)+8*(reg>>2)+4*(lane>>5)) into one B fragment (k-slice) for the
// next step: pack f16 pairs along consecutive rows, then exchange halves so
// each lane-half holds its k-octet. v_permlane32_swap_b32: a'={a.lo,b.lo},
// b'={a.hi,b.hi}.
#define PACKGRP(Csrc, base, dst) { \
    unsigned q0 = B2U(__builtin_amdgcn_cvt_pkrtz(Csrc[(base)+0], Csrc[(base)+1])); \
    unsigned q2 = B2U(__builtin_amdgcn_cvt_pkrtz(Csrc[(base)+2], Csrc[(base)+3])); \
    unsigned q4 = B2U(__builtin_amdgcn_cvt_pkrtz(Csrc[(base)+4], Csrc[(base)+5])); \
    unsigned q6 = B2U(__builtin_amdgcn_cvt_pkrtz(Csrc[(base)+6], Csrc[(base)+7])); \
    asm("v_permlane32_swap_b32 %0, %1" : "+v"(q0), "+v"(q4)); \
    asm("v_permlane32_swap_b32 %0, %1" : "+v"(q2), "+v"(q6)); \
    u32x4 qv = {q0, q2, q4, q6}; \
    dst = __builtin_bit_cast(half8, qv); }

#define STORET(Ct, t4) { \
    _Pragma("unroll") \
    for (int g = 0; g < 4; ++g) { \
        u32x2 pv; \
        pv.x = B2U(__builtin_amdgcn_cvt_pkrtz(Ct[4*g+0], Ct[4*g+1])); \
        pv.y = B2U(__builtin_amdgcn_cvt_pkrtz(Ct[4*g+2], Ct[4*g+3])); \
        *(u32x2*)(wm + (t4)*1024 + g*256 + lane*4) = pv; } }

__device__ __forceinline__ void midseg(const float* __restrict__ pred,
                                       const float* __restrict__ trans,
                                       int b, int lane, int sl, int s,
                                       _Float16* __restrict__ wsM,
                                       int* __restrict__ wsKm)
{
    const int nm = (sl - 128) >> 7;
    if (s >= nm) return;
    const int t0 = 128 * (1 + s);
    const int H  = lane >> 5;
    const int j0 = lane & 31;

    // Constant A-basis: VA[mt][s4][e] = exp(trans[k][32*mt+j0]), k=16*s4+8*H+e.
    half8 VA[2][4];
    #pragma unroll
    for (int mt = 0; mt < 2; ++mt)
        #pragma unroll
        for (int s4 = 0; s4 < 4; ++s4) {
            half8 va;
            #pragma unroll
            for (int e = 0; e < 8; ++e) {
                int k = 16 * s4 + 8 * H + e;
                va[e] = (_Float16)EXPE(trans[k * 66 + 32 * mt + j0]);
            }
            VA[mt][s4] = va;
        }

    // B = identity (M starts as I; step i multiplies diag(E)*V^T on the left).
    half8 Bf[4][2];
    #pragma unroll
    for (int s4 = 0; s4 < 4; ++s4)
        #pragma unroll
        for (int nt = 0; nt < 2; ++nt) {
            half8 bb;
            #pragma unroll
            for (int e = 0; e < 8; ++e)
                bb[e] = (16 * s4 + 8 * H + e == 32 * nt + j0) ? (_Float16)1.f
                                                              : (_Float16)0.f;
            Bf[s4][nt] = bb;
        }

    const float* pp = pred + (size_t)b * 65536 + j0;
    float a0 = pp[(size_t)t0 * 64],        a1 = pp[(size_t)t0 * 64 + 32];
    float q0 = pp[(size_t)(t0 + 1) * 64],  q1 = pp[(size_t)(t0 + 1) * 64 + 32];

    const f32x16 Z16 = {0.f,0.f,0.f,0.f,0.f,0.f,0.f,0.f,
                        0.f,0.f,0.f,0.f,0.f,0.f,0.f,0.f};
    f32x16 C00 = Z16, C01 = Z16, C10 = Z16, C11 = Z16;
    int   K   = 0;
    float scf = 1.0f;

    for (int i = 0; i < 128; ++i) {
        int tn = t0 + i + 2; if (tn > 1023) tn = 1023;
        float n0 = pp[(size_t)tn * 64], n1 = pp[(size_t)tn * 64 + 32];

        if (i > 0) {
            // pow-2 renorm ref = sum of tile00 regs at lane0 (stable vs E-tails)
            float sr = ((C00[0]+C00[1])+(C00[2]+C00[3]))+((C00[4]+C00[5])+(C00[6]+C00[7]))
                     + ((C00[8]+C00[9])+(C00[10]+C00[11]))+((C00[12]+C00[13])+(C00[14]+C00[15]));
            unsigned cb = (unsigned)__builtin_amdgcn_readfirstlane((int)__float_as_uint(sr));
            int kk = (int)((cb >> 23) & 255u) - 129;   // ilogb(sr) - 2
            K += kk;
            scf = __uint_as_float((unsigned)(127 - kk) << 23);
            // repack C (raw) -> next-step B fragments
            PACKGRP(C00, 0, Bf[0][0]) PACKGRP(C00, 8, Bf[1][0])
            PACKGRP(C10, 0, Bf[2][0]) PACKGRP(C10, 8, Bf[3][0])
            PACKGRP(C01, 0, Bf[0][1]) PACKGRP(C01, 8, Bf[1][1])
            PACKGRP(C11, 0, Bf[2][1]) PACKGRP(C11, 8, Bf[3][1])
        }
        float e0 = EXPE(a0) * scf, e1 = EXPE(a1) * scf;
        _Float16 h0 = (_Float16)e0, h1 = (_Float16)e1;
        half8 E0v = {h0,h0,h0,h0,h0,h0,h0,h0};
        half8 E1v = {h1,h1,h1,h1,h1,h1,h1,h1};
        half8 A00 = VA[0][0]*E0v, A01 = VA[0][1]*E0v, A02 = VA[0][2]*E0v, A03 = VA[0][3]*E0v;
        half8 A10 = VA[1][0]*E1v, A11 = VA[1][1]*E1v, A12 = VA[1][2]*E1v, A13 = VA[1][3]*E1v;

        C00 = MFMA16(A00, Bf[0][0], MFMA16(A01, Bf[1][0], MFMA16(A02, Bf[2][0], MFMA16(A03, Bf[3][0], Z16))));
        C01 = MFMA16(A00, Bf[0][1], MFMA16(A01, Bf[1][1], MFMA16(A02, Bf[2][1], MFMA16(A03, Bf[3][1], Z16))));
        C10 = MFMA16(A10, Bf[0][0], MFMA16(A11, Bf[1][0], MFMA16(A12, Bf[2][0], MFMA16(A13, Bf[3][0], Z16))));
        C11 = MFMA16(A10, Bf[0][1], MFMA16(A11, Bf[1][1], MFMA16(A12, Bf[2][1], MFMA16(A13, Bf[3][1], Z16))));

        a0 = q0; a1 = q1; q0 = n0; q1 = n1;
    }

    // store M_s as f16: half-idx = tile*1024 + (reg>>2)*256 + lane*4 + (reg&3)
    _Float16* wm = wsM + (size_t)(b * 7 + s) * 4096;
    STORET(C00, 0) STORET(C01, 1) STORET(C10, 2) STORET(C11, 3)
    if (lane == 0) wsKm[b * 7 + s] = K;
}

// ---------------- kernels ----------------

__global__ __launch_bounds__(64) __attribute__((amdgpu_waves_per_eu(2)))
void chain_kernel(const float* __restrict__ pred,
                  const float* __restrict__ trans,
                  const int*   __restrict__ ref,
                  const int*   __restrict__ seqlen,
                  float* __restrict__ wsA, float* __restrict__ wsB,
                  int* __restrict__ wsKf, int* __restrict__ wsKb,
                  _Float16* __restrict__ wsM, int* __restrict__ wsKm,
                  float* __restrict__ out)
{
    const int role = blockIdx.x >> 8;
    const int b    = blockIdx.x & 255;
    const int lane = threadIdx.x;
    const int sl   = seqlen[b];

    if (role == 0) {
        chain<true>(pred, trans, b, lane, sl, 128, wsA, wsKf);
    } else if (role == 1) {
        const int nm = (sl - 128) >> 7;
        const int tb = 128 * (1 + nm);
        chain<false>(pred, trans, b, lane, sl, tb, wsB, wsKb);
    } else if (role == 2) {
        // gold-path score
        const int*   rb = ref  + b * 1024;
        const float* pg = pred + (size_t)b * 65536;
        float acc = 0.f;
        for (int t = lane; t <= sl; t += 64) {
            int from = (t == 0) ? 64 : rb[t - 1];
            int cur  = (t < sl) ? rb[t] : 65;
            acc += trans[from * 66 + cur];
            if (t < sl) acc += pg[t * 64 + cur];
        }
        #pragma unroll
        for (int off = 32; off; off >>= 1) acc += __shfl_xor(acc, off, 64);
        if (lane == 0) atomicAdd(out, -acc);
    } else {
        midseg(pred, trans, b, lane, sl, role - 3, wsM, wsKm);
    }
}

__global__ __launch_bounds__(64) void combine_kernel(
    const float* __restrict__ wsA, const float* __restrict__ wsB,
    const _Float16* __restrict__ wsM,
    const int* __restrict__ wsKf, const int* __restrict__ wsKb,
    const int* __restrict__ wsKm, const int* __restrict__ seqlen,
    float* __restrict__ out)
{
    const int b = blockIdx.x, j = threadIdx.x;
    const int sl = seqlen[b];
    const int nm = (sl - 128) >> 7;

    float v = wsA[b * 64 + j];
    int   K = wsKf[b] + wsKb[b];

    const int mt = j >> 5, hi = (j >> 2) & 1, g = (j >> 3) & 3, e = j & 3;
    const _Float16* mb = wsM + (size_t)b * 7 * 4096 + mt * 2048 + g * 256 + hi * 128 + e;

    for (int s = 0; s < nm; ++s) {
        K += wsKm[b * 7 + s];
        const _Float16* ms = mb + (size_t)s * 4096;
        float acc = 0.f;
        #pragma unroll
        for (int c = 0; c < 64; ++c) {
            float m  = (float)ms[(c >> 5) * 1024 + (c & 31) * 4];
            float vc = __uint_as_float(
                (unsigned)__builtin_amdgcn_readlane((int)__float_as_uint(v), c));
            acc = fmaf(m, vc, acc);
        }
        unsigned ab = (unsigned)__builtin_amdgcn_readfirstlane((int)__float_as_uint(acc));
        int k2 = (int)((ab >> 23) & 255u) - 127;
        K += k2;
        v = acc * __uint_as_float((unsigned)(127 - k2) << 23);
    }

    float z = v * wsB[b * 64 + j];
    #pragma unroll
    for (int off = 32; off; off >>= 1) z += __shfl_xor(z, off, 64);
    if (j == 0) {
        float res = LN2 * (__builtin_amdgcn_logf(z) + (float)K);
        atomicAdd(out, res);
    }
}

extern "C" void kernel_launch(void* const* d_in, const int* in_sizes, int n_in,
                              void* d_out, int out_size, void* d_ws, size_t ws_size,
                              hipStream_t stream) {
    const float* pred   = (const float*)d_in[0];
    const float* trans  = (const float*)d_in[1];
    const int*   ref    = (const int*)d_in[2];
    const int*   seqlen = (const int*)d_in[3];
    float* out = (float*)d_out;

    float* wsA  = (float*)d_ws;            // 256*64 f32
    float* wsB  = wsA + 256 * 64;          // 256*64 f32
    int*   wsKf = (int*)(wsB + 256 * 64);  // 256 i32
    int*   wsKb = wsKf + 256;              // 256 i32
    int*   wsKm = wsKb + 256;              // 256*7 i32
    _Float16* wsM = (_Float16*)(wsKm + 256 * 7);  // 256*7*4096 f16 (~14.7 MB)

    hipMemsetAsync(out, 0, sizeof(float), stream);
    chain_kernel<<<2560, 64, 0, stream>>>(pred, trans, ref, seqlen,
                                          wsA, wsB, wsKf, wsKb, wsM, wsKm, out);
    combine_kernel<<<256, 64, 0, stream>>>(wsA, wsB, wsM, wsKf, wsKb, wsKm,
                                           seqlen, out);
}